// Round 1
// baseline (847.997 us; speedup 1.0000x reference)
//
#include <hip/hip_runtime.h>

#define N_NODES 50000
#define N_EDGES 800000
#define D_FEAT 64
#define K_HOPS 8
#define OUT_STRIDE ((K_HOPS + 1) * D_FEAT)  // 576

// ---------------- ws layout (bytes, 256-aligned) ----------------
#define ALIGN256(x) (((x) + 255) & ~(size_t)255)
static const size_t OFF_DEG    = 0;                                         // int[N]
static const size_t OFF_HIST   = ALIGN256(OFF_DEG    + N_NODES * 4);        // int[N]
static const size_t OFF_OFFARR = ALIGN256(OFF_HIST   + N_NODES * 4);        // int[N+1]
static const size_t OFF_CURSOR = ALIGN256(OFF_OFFARR + (N_NODES + 1) * 4);  // int[N]
static const size_t OFF_BSUM   = ALIGN256(OFF_CURSOR + N_NODES * 4);        // int[64]
static const size_t OFF_DINV   = ALIGN256(OFF_BSUM   + 64 * 4);             // float[N]
static const size_t OFF_CSRC   = ALIGN256(OFF_DINV   + N_NODES * 4);        // int[E]
static const size_t OFF_CNORM  = ALIGN256(OFF_CSRC   + N_EDGES * 4);        // float[E]

#define SCAN_BLOCK_ELEMS 1024
#define SCAN_NB ((N_NODES + SCAN_BLOCK_ELEMS - 1) / SCAN_BLOCK_ELEMS)  // 49

// ---------------- preprocessing kernels ----------------

__global__ void k_init(int* __restrict__ deg, int* __restrict__ hist) {
    int i = blockIdx.x * blockDim.x + threadIdx.x;
    if (i < N_NODES) { deg[i] = 1; hist[i] = 0; }  // deg starts at 1 (self loop w=1)
}

__global__ void k_count(const int* __restrict__ src, const int* __restrict__ dst,
                        int* __restrict__ deg, int* __restrict__ hist) {
    int e = blockIdx.x * blockDim.x + threadIdx.x;
    if (e >= N_EDGES) return;
    int s = src[e], d = dst[e];
    if (s != d) {               // self-loop input edges have weight 0 -> dropped
        atomicAdd(&deg[s], 1);  // deg is over `row` = src
        atomicAdd(&hist[d], 1); // CSR grouped by aggregation target dst
    }
}

__global__ void k_dinv(const int* __restrict__ deg, float* __restrict__ dinv) {
    int i = blockIdx.x * blockDim.x + threadIdx.x;
    if (i < N_NODES) dinv[i] = rsqrtf((float)deg[i]);  // deg >= 1 always
}

// scan stage 1: per-block sums of 1024-elem chunks
__global__ void k_scan_sums(const int* __restrict__ hist, int* __restrict__ bsum) {
    __shared__ int lds[256];
    int b = blockIdx.x, t = threadIdx.x;
    int base = b * SCAN_BLOCK_ELEMS;
    int s = 0;
    for (int j = t; j < SCAN_BLOCK_ELEMS; j += 256) {
        int idx = base + j;
        if (idx < N_NODES) s += hist[idx];
    }
    lds[t] = s; __syncthreads();
    for (int str = 128; str > 0; str >>= 1) {
        if (t < str) lds[t] += lds[t + str];
        __syncthreads();
    }
    if (t == 0) bsum[b] = lds[0];
}

// scan stage 2: single-wave exclusive scan of the 49 block sums
__global__ void k_scan_top(int* __restrict__ bsum) {
    int lane = threadIdx.x;  // blockDim = 64
    int orig = (lane < SCAN_NB) ? bsum[lane] : 0;
    int v = orig;
    for (int d = 1; d < 64; d <<= 1) {
        int u = __shfl_up(v, d, 64);
        if (lane >= d) v += u;
    }
    if (lane < SCAN_NB) bsum[lane] = v - orig;  // exclusive
}

// scan stage 3: down-sweep, write off[] and cursor[] (cursor = working copy)
__global__ void k_scan_down(const int* __restrict__ hist, const int* __restrict__ bsum,
                            int* __restrict__ off, int* __restrict__ cursor) {
    __shared__ int lds[256];
    int b = blockIdx.x, t = threadIdx.x;
    int base = b * SCAN_BLOCK_ELEMS + t * 4;
    int v[4];
    #pragma unroll
    for (int j = 0; j < 4; ++j) v[j] = (base + j < N_NODES) ? hist[base + j] : 0;
    int tsum = v[0] + v[1] + v[2] + v[3];
    lds[t] = tsum; __syncthreads();
    int x = tsum;
    for (int d = 1; d < 256; d <<= 1) {   // Hillis-Steele inclusive scan
        int u = (t >= d) ? lds[t - d] : 0;
        __syncthreads();
        x += u;
        lds[t] = x;
        __syncthreads();
    }
    int p = (x - tsum) + bsum[b];  // exclusive prefix for this thread's first elem
    #pragma unroll
    for (int j = 0; j < 4; ++j) {
        int idx = base + j;
        if (idx < N_NODES) { off[idx] = p; cursor[idx] = p; p += v[j]; }
        else if (idx == N_NODES) { off[idx] = p; }  // total edge count
    }
}

__global__ void k_scatter(const int* __restrict__ src, const int* __restrict__ dst,
                          const float* __restrict__ dinv, int* __restrict__ cursor,
                          int* __restrict__ csr_src, float* __restrict__ csr_norm) {
    int e = blockIdx.x * blockDim.x + threadIdx.x;
    if (e >= N_EDGES) return;
    int s = src[e], d = dst[e];
    if (s == d) return;
    int pos = atomicAdd(&cursor[d], 1);
    csr_src[pos] = s;
    csr_norm[pos] = dinv[s] * dinv[d];
}

// ---------------- compute kernels ----------------

// x0: feature -> out columns [0,64), float4 vectorized
__global__ void k_copy_x0(const float4* __restrict__ feat, float4* __restrict__ out) {
    int t = blockIdx.x * blockDim.x + threadIdx.x;  // over N*16
    if (t >= N_NODES * 16) return;
    int row = t >> 4, c = t & 15;
    out[(size_t)row * (OUT_STRIDE / 4) + c] = feat[t];
}

// one wave per node; lane = feature dim (D_FEAT == 64 == wave width)
__global__ __launch_bounds__(256) void k_hop(
    const float* __restrict__ prev, int pstride,
    float* __restrict__ next,  // row stride OUT_STRIDE
    const int* __restrict__ off, const int* __restrict__ csr_src,
    const float* __restrict__ csr_norm, const float* __restrict__ dinv) {
    int wid = (blockIdx.x * blockDim.x + threadIdx.x) >> 6;
    int lane = threadIdx.x & 63;
    if (wid >= N_NODES) return;
    float di = dinv[wid];
    float acc = di * di * prev[(size_t)wid * pstride + lane];  // self loop: 1/deg
    int e0 = off[wid], e1 = off[wid + 1];
    for (int e = e0; e < e1; ++e) {
        int s = csr_src[e];
        float w = csr_norm[e];
        acc = fmaf(w, prev[(size_t)s * pstride + lane], acc);
    }
    next[(size_t)wid * OUT_STRIDE + lane] = acc;
}

// ---------------- launch ----------------

extern "C" void kernel_launch(void* const* d_in, const int* in_sizes, int n_in,
                              void* d_out, int out_size, void* d_ws, size_t ws_size,
                              hipStream_t stream) {
    const float* feature = (const float*)d_in[0];
    const int* edge = (const int*)d_in[1];
    const int* src = edge;            // edge_index[0]
    const int* dst = edge + N_EDGES;  // edge_index[1]
    float* out = (float*)d_out;
    char* ws = (char*)d_ws;

    int*   deg      = (int*)(ws + OFF_DEG);
    int*   hist     = (int*)(ws + OFF_HIST);
    int*   off      = (int*)(ws + OFF_OFFARR);
    int*   cursor   = (int*)(ws + OFF_CURSOR);
    int*   bsum     = (int*)(ws + OFF_BSUM);
    float* dinv     = (float*)(ws + OFF_DINV);
    int*   csr_src  = (int*)(ws + OFF_CSRC);
    float* csr_norm = (float*)(ws + OFF_CNORM);

    const int TB = 256;
    // ---- build normalization + CSR (must re-run every call: ws is re-poisoned)
    k_init<<<(N_NODES + TB - 1) / TB, TB, 0, stream>>>(deg, hist);
    k_count<<<(N_EDGES + TB - 1) / TB, TB, 0, stream>>>(src, dst, deg, hist);
    k_dinv<<<(N_NODES + TB - 1) / TB, TB, 0, stream>>>(deg, dinv);
    k_scan_sums<<<SCAN_NB, 256, 0, stream>>>(hist, bsum);
    k_scan_top<<<1, 64, 0, stream>>>(bsum);
    k_scan_down<<<SCAN_NB, 256, 0, stream>>>(hist, bsum, off, cursor);
    k_scatter<<<(N_EDGES + TB - 1) / TB, TB, 0, stream>>>(src, dst, dinv, cursor,
                                                          csr_src, csr_norm);
    // ---- x0 copy
    k_copy_x0<<<(N_NODES * 16 + TB - 1) / TB, TB, 0, stream>>>(
        (const float4*)feature, (float4*)out);
    // ---- K hops: hop k reads column block k-1 (hop 1 reads compact feature)
    const int hop_blocks = (N_NODES * 64 + TB - 1) / TB;  // 4 waves/block, 1 node/wave
    for (int k = 1; k <= K_HOPS; ++k) {
        const float* prev = (k == 1) ? feature : (out + (size_t)(k - 1) * D_FEAT);
        int pstride = (k == 1) ? D_FEAT : OUT_STRIDE;
        float* next = out + (size_t)k * D_FEAT;
        k_hop<<<hop_blocks, TB, 0, stream>>>(prev, pstride, next, off, csr_src,
                                             csr_norm, dinv);
    }
}

// Round 2
// 493.880 us; speedup vs baseline: 1.7170x; 1.7170x over previous
//
#include <hip/hip_runtime.h>

#define N_NODES 50000
#define N_EDGES 800000
#define D_FEAT 64
#define K_HOPS 8
#define OUT_STRIDE ((K_HOPS + 1) * D_FEAT)  // 576

// ---------------- ws layout (bytes, 256-aligned) ----------------
#define ALIGN256(x) (((x) + 255) & ~(size_t)255)
static const size_t OFF_DEG    = 0;                                         // int[N]
static const size_t OFF_HIST   = ALIGN256(OFF_DEG    + N_NODES * 4);        // int[N]
static const size_t OFF_OFFARR = ALIGN256(OFF_HIST   + N_NODES * 4);        // int[N+1]
static const size_t OFF_CURSOR = ALIGN256(OFF_OFFARR + (N_NODES + 1) * 4);  // int[N]
static const size_t OFF_BSUM   = ALIGN256(OFF_CURSOR + N_NODES * 4);        // int[64]
static const size_t OFF_DINV   = ALIGN256(OFF_BSUM   + 64 * 4);             // float[N]
static const size_t OFF_CSR    = ALIGN256(OFF_DINV   + N_NODES * 4);        // int2[E]

#define SCAN_BLOCK_ELEMS 1024
#define SCAN_NB ((N_NODES + SCAN_BLOCK_ELEMS - 1) / SCAN_BLOCK_ELEMS)  // 49

// ---------------- preprocessing kernels ----------------

__global__ void k_init(int* __restrict__ deg, int* __restrict__ hist) {
    int i = blockIdx.x * blockDim.x + threadIdx.x;
    if (i < N_NODES) { deg[i] = 1; hist[i] = 0; }  // deg starts at 1 (self loop w=1)
}

// 4 edges per thread, int4 vector loads (N_EDGES % 4 == 0)
__global__ void k_count(const int4* __restrict__ src4, const int4* __restrict__ dst4,
                        int* __restrict__ deg, int* __restrict__ hist) {
    int t = blockIdx.x * blockDim.x + threadIdx.x;
    if (t >= N_EDGES / 4) return;
    int4 s = src4[t], d = dst4[t];
    if (s.x != d.x) { atomicAdd(&deg[s.x], 1); atomicAdd(&hist[d.x], 1); }
    if (s.y != d.y) { atomicAdd(&deg[s.y], 1); atomicAdd(&hist[d.y], 1); }
    if (s.z != d.z) { atomicAdd(&deg[s.z], 1); atomicAdd(&hist[d.z], 1); }
    if (s.w != d.w) { atomicAdd(&deg[s.w], 1); atomicAdd(&hist[d.w], 1); }
}

__global__ void k_dinv(const int* __restrict__ deg, float* __restrict__ dinv) {
    int i = blockIdx.x * blockDim.x + threadIdx.x;
    if (i < N_NODES) dinv[i] = rsqrtf((float)deg[i]);  // deg >= 1 always
}

// scan stage 1: per-block sums of 1024-elem chunks
__global__ void k_scan_sums(const int* __restrict__ hist, int* __restrict__ bsum) {
    __shared__ int lds[256];
    int b = blockIdx.x, t = threadIdx.x;
    int base = b * SCAN_BLOCK_ELEMS;
    int s = 0;
    for (int j = t; j < SCAN_BLOCK_ELEMS; j += 256) {
        int idx = base + j;
        if (idx < N_NODES) s += hist[idx];
    }
    lds[t] = s; __syncthreads();
    for (int str = 128; str > 0; str >>= 1) {
        if (t < str) lds[t] += lds[t + str];
        __syncthreads();
    }
    if (t == 0) bsum[b] = lds[0];
}

// scan stage 2: single-wave exclusive scan of the 49 block sums
__global__ void k_scan_top(int* __restrict__ bsum) {
    int lane = threadIdx.x;  // blockDim = 64
    int orig = (lane < SCAN_NB) ? bsum[lane] : 0;
    int v = orig;
    for (int d = 1; d < 64; d <<= 1) {
        int u = __shfl_up(v, d, 64);
        if (lane >= d) v += u;
    }
    if (lane < SCAN_NB) bsum[lane] = v - orig;  // exclusive
}

// scan stage 3: down-sweep, write off[] and cursor[]
__global__ void k_scan_down(const int* __restrict__ hist, const int* __restrict__ bsum,
                            int* __restrict__ off, int* __restrict__ cursor) {
    __shared__ int lds[256];
    int b = blockIdx.x, t = threadIdx.x;
    int base = b * SCAN_BLOCK_ELEMS + t * 4;
    int v[4];
    #pragma unroll
    for (int j = 0; j < 4; ++j) v[j] = (base + j < N_NODES) ? hist[base + j] : 0;
    int tsum = v[0] + v[1] + v[2] + v[3];
    lds[t] = tsum; __syncthreads();
    int x = tsum;
    for (int d = 1; d < 256; d <<= 1) {   // Hillis-Steele inclusive scan
        int u = (t >= d) ? lds[t - d] : 0;
        __syncthreads();
        x += u;
        lds[t] = x;
        __syncthreads();
    }
    int p = (x - tsum) + bsum[b];
    #pragma unroll
    for (int j = 0; j < 4; ++j) {
        int idx = base + j;
        if (idx < N_NODES) { off[idx] = p; cursor[idx] = p; p += v[j]; }
        else if (idx == N_NODES) { off[idx] = p; }
    }
}

// scatter (src, norm) packed as int2, 2 edges per thread via int2 loads
__global__ void k_scatter(const int2* __restrict__ src2, const int2* __restrict__ dst2,
                          const float* __restrict__ dinv, int* __restrict__ cursor,
                          int2* __restrict__ csr) {
    int t = blockIdx.x * blockDim.x + threadIdx.x;
    if (t >= N_EDGES / 2) return;
    int2 s = src2[t], d = dst2[t];
    if (s.x != d.x) {
        int pos = atomicAdd(&cursor[d.x], 1);
        csr[pos] = make_int2(s.x, __float_as_int(dinv[s.x] * dinv[d.x]));
    }
    if (s.y != d.y) {
        int pos = atomicAdd(&cursor[d.y], 1);
        csr[pos] = make_int2(s.y, __float_as_int(dinv[s.y] * dinv[d.y]));
    }
}

// ---------------- compute kernels ----------------

// x0: feature -> out columns [0,64), float4 vectorized
__global__ void k_copy_x0(const float4* __restrict__ feat, float4* __restrict__ out) {
    int t = blockIdx.x * blockDim.x + threadIdx.x;  // over N*16
    if (t >= N_NODES * 16) return;
    int row = t >> 4, c = t & 15;
    out[(size_t)row * (OUT_STRIDE / 4) + c] = feat[t];
}

// one wave per node; lane = feature dim. Edge loop unrolled x8 with 4
// independent accumulators -> 8 gathers in flight per wave (MLP).
__global__ __launch_bounds__(256) void k_hop(
    const float* __restrict__ prev, int pstride,
    float* __restrict__ next,  // row stride OUT_STRIDE
    const int* __restrict__ off, const int2* __restrict__ csr,
    const float* __restrict__ dinv) {
    int wid = (blockIdx.x * blockDim.x + threadIdx.x) >> 6;
    int lane = threadIdx.x & 63;
    if (wid >= N_NODES) return;
    int e0 = off[wid], e1 = off[wid + 1];
    float di = dinv[wid];
    float acc0 = di * di * prev[(size_t)wid * pstride + lane];  // self loop: 1/deg
    float acc1 = 0.f, acc2 = 0.f, acc3 = 0.f;
    int e = e0;
    for (; e + 8 <= e1; e += 8) {
        int2 c0 = csr[e + 0], c1 = csr[e + 1], c2 = csr[e + 2], c3 = csr[e + 3];
        int2 c4 = csr[e + 4], c5 = csr[e + 5], c6 = csr[e + 6], c7 = csr[e + 7];
        float p0 = prev[(size_t)c0.x * pstride + lane];
        float p1 = prev[(size_t)c1.x * pstride + lane];
        float p2 = prev[(size_t)c2.x * pstride + lane];
        float p3 = prev[(size_t)c3.x * pstride + lane];
        float p4 = prev[(size_t)c4.x * pstride + lane];
        float p5 = prev[(size_t)c5.x * pstride + lane];
        float p6 = prev[(size_t)c6.x * pstride + lane];
        float p7 = prev[(size_t)c7.x * pstride + lane];
        acc0 = fmaf(__int_as_float(c0.y), p0, acc0);
        acc1 = fmaf(__int_as_float(c1.y), p1, acc1);
        acc2 = fmaf(__int_as_float(c2.y), p2, acc2);
        acc3 = fmaf(__int_as_float(c3.y), p3, acc3);
        acc0 = fmaf(__int_as_float(c4.y), p4, acc0);
        acc1 = fmaf(__int_as_float(c5.y), p5, acc1);
        acc2 = fmaf(__int_as_float(c6.y), p6, acc2);
        acc3 = fmaf(__int_as_float(c7.y), p7, acc3);
    }
    if (e + 4 <= e1) {
        int2 c0 = csr[e + 0], c1 = csr[e + 1], c2 = csr[e + 2], c3 = csr[e + 3];
        float p0 = prev[(size_t)c0.x * pstride + lane];
        float p1 = prev[(size_t)c1.x * pstride + lane];
        float p2 = prev[(size_t)c2.x * pstride + lane];
        float p3 = prev[(size_t)c3.x * pstride + lane];
        acc0 = fmaf(__int_as_float(c0.y), p0, acc0);
        acc1 = fmaf(__int_as_float(c1.y), p1, acc1);
        acc2 = fmaf(__int_as_float(c2.y), p2, acc2);
        acc3 = fmaf(__int_as_float(c3.y), p3, acc3);
        e += 4;
    }
    for (; e < e1; ++e) {
        int2 c = csr[e];
        acc0 = fmaf(__int_as_float(c.y), prev[(size_t)c.x * pstride + lane], acc0);
    }
    next[(size_t)wid * OUT_STRIDE + lane] = (acc0 + acc1) + (acc2 + acc3);
}

// ---------------- launch ----------------

extern "C" void kernel_launch(void* const* d_in, const int* in_sizes, int n_in,
                              void* d_out, int out_size, void* d_ws, size_t ws_size,
                              hipStream_t stream) {
    const float* feature = (const float*)d_in[0];
    const int* edge = (const int*)d_in[1];
    const int* src = edge;            // edge_index[0]
    const int* dst = edge + N_EDGES;  // edge_index[1]
    float* out = (float*)d_out;
    char* ws = (char*)d_ws;

    int*   deg    = (int*)(ws + OFF_DEG);
    int*   hist   = (int*)(ws + OFF_HIST);
    int*   off    = (int*)(ws + OFF_OFFARR);
    int*   cursor = (int*)(ws + OFF_CURSOR);
    int*   bsum   = (int*)(ws + OFF_BSUM);
    float* dinv   = (float*)(ws + OFF_DINV);
    int2*  csr    = (int2*)(ws + OFF_CSR);

    const int TB = 256;
    // ---- build normalization + CSR (re-run every call: ws is re-poisoned)
    k_init<<<(N_NODES + TB - 1) / TB, TB, 0, stream>>>(deg, hist);
    k_count<<<(N_EDGES / 4 + TB - 1) / TB, TB, 0, stream>>>(
        (const int4*)src, (const int4*)dst, deg, hist);
    k_dinv<<<(N_NODES + TB - 1) / TB, TB, 0, stream>>>(deg, dinv);
    k_scan_sums<<<SCAN_NB, 256, 0, stream>>>(hist, bsum);
    k_scan_top<<<1, 64, 0, stream>>>(bsum);
    k_scan_down<<<SCAN_NB, 256, 0, stream>>>(hist, bsum, off, cursor);
    k_scatter<<<(N_EDGES / 2 + TB - 1) / TB, TB, 0, stream>>>(
        (const int2*)src, (const int2*)dst, dinv, cursor, csr);
    // ---- x0 copy
    k_copy_x0<<<(N_NODES * 16 + TB - 1) / TB, TB, 0, stream>>>(
        (const float4*)feature, (float4*)out);
    // ---- K hops: hop k reads column block k-1 (hop 1 reads compact feature)
    const int hop_blocks = (N_NODES * 64 + TB - 1) / TB;  // 4 waves/block
    for (int k = 1; k <= K_HOPS; ++k) {
        const float* prev = (k == 1) ? feature : (out + (size_t)(k - 1) * D_FEAT);
        int pstride = (k == 1) ? D_FEAT : OUT_STRIDE;
        float* next = out + (size_t)k * D_FEAT;
        k_hop<<<hop_blocks, TB, 0, stream>>>(prev, pstride, next, off, csr, dinv);
    }
}

// Round 3
// 480.953 us; speedup vs baseline: 1.7632x; 1.0269x over previous
//
#include <hip/hip_runtime.h>

#define N_NODES 50000
#define N_EDGES 800000
#define D_FEAT 64
#define K_HOPS 8
#define OUT_STRIDE ((K_HOPS + 1) * D_FEAT)  // 576

// ---------------- ws layout (bytes) ----------------
// deg and hist are deliberately CONTIGUOUS so one hipMemsetAsync zeroes both.
#define ALIGN256(x) (((x) + 255) & ~(size_t)255)
static const size_t OFF_DEG    = 0;                                         // int[N]
static const size_t OFF_HIST   = OFF_DEG + N_NODES * 4;                     // int[N] (contiguous!)
static const size_t OFF_OFFARR = ALIGN256(OFF_HIST   + N_NODES * 4);        // int[N+1]
static const size_t OFF_CURSOR = ALIGN256(OFF_OFFARR + (N_NODES + 1) * 4);  // int[N]
static const size_t OFF_BSUM   = ALIGN256(OFF_CURSOR + N_NODES * 4);        // int[64]
static const size_t OFF_CSR    = ALIGN256(OFF_BSUM   + 64 * 4);             // int2[E]

#define SCAN_BLOCK_ELEMS 1024
#define SCAN_NB ((N_NODES + SCAN_BLOCK_ELEMS - 1) / SCAN_BLOCK_ELEMS)  // 49

// ---------------- preprocessing kernels ----------------

// deg[i] = out-degree of i (self-loops dropped); coefficient uses deg+1.
// 1 edge per thread: maximize wave count -> maximize outstanding atomics.
__global__ void k_count(const int* __restrict__ src, const int* __restrict__ dst,
                        int* __restrict__ deg, int* __restrict__ hist) {
    int e = blockIdx.x * blockDim.x + threadIdx.x;
    if (e >= N_EDGES) return;
    int s = src[e], d = dst[e];
    if (s != d) {
        atomicAdd(&deg[s], 1);
        atomicAdd(&hist[d], 1);
    }
}

// scan stage 1: per-block sums of 1024-elem chunks
__global__ void k_scan_sums(const int* __restrict__ hist, int* __restrict__ bsum) {
    __shared__ int lds[256];
    int b = blockIdx.x, t = threadIdx.x;
    int base = b * SCAN_BLOCK_ELEMS;
    int s = 0;
    for (int j = t; j < SCAN_BLOCK_ELEMS; j += 256) {
        int idx = base + j;
        if (idx < N_NODES) s += hist[idx];
    }
    lds[t] = s; __syncthreads();
    for (int str = 128; str > 0; str >>= 1) {
        if (t < str) lds[t] += lds[t + str];
        __syncthreads();
    }
    if (t == 0) bsum[b] = lds[0];
}

// scan stage 2: single-wave exclusive scan of the 49 block sums
__global__ void k_scan_top(int* __restrict__ bsum) {
    int lane = threadIdx.x;  // blockDim = 64
    int orig = (lane < SCAN_NB) ? bsum[lane] : 0;
    int v = orig;
    for (int d = 1; d < 64; d <<= 1) {
        int u = __shfl_up(v, d, 64);
        if (lane >= d) v += u;
    }
    if (lane < SCAN_NB) bsum[lane] = v - orig;  // exclusive
}

// scan stage 3: down-sweep, write off[] and cursor[]
__global__ void k_scan_down(const int* __restrict__ hist, const int* __restrict__ bsum,
                            int* __restrict__ off, int* __restrict__ cursor) {
    __shared__ int lds[256];
    int b = blockIdx.x, t = threadIdx.x;
    int base = b * SCAN_BLOCK_ELEMS + t * 4;
    int v[4];
    #pragma unroll
    for (int j = 0; j < 4; ++j) v[j] = (base + j < N_NODES) ? hist[base + j] : 0;
    int tsum = v[0] + v[1] + v[2] + v[3];
    lds[t] = tsum; __syncthreads();
    int x = tsum;
    for (int d = 1; d < 256; d <<= 1) {   // Hillis-Steele inclusive scan
        int u = (t >= d) ? lds[t - d] : 0;
        __syncthreads();
        x += u;
        lds[t] = x;
        __syncthreads();
    }
    int p = (x - tsum) + bsum[b];
    #pragma unroll
    for (int j = 0; j < 4; ++j) {
        int idx = base + j;
        if (idx < N_NODES) { off[idx] = p; cursor[idx] = p; p += v[j]; }
        else if (idx == N_NODES) { off[idx] = p; }
    }
}

// scatter (src, norm) packed as int2; norm computed inline from deg.
// 1 edge per thread for max outstanding atomics.
__global__ void k_scatter(const int* __restrict__ src, const int* __restrict__ dst,
                          const int* __restrict__ deg, int* __restrict__ cursor,
                          int2* __restrict__ csr) {
    int e = blockIdx.x * blockDim.x + threadIdx.x;
    if (e >= N_EDGES) return;
    int s = src[e], d = dst[e];
    if (s == d) return;
    float n = rsqrtf((float)(deg[s] + 1)) * rsqrtf((float)(deg[d] + 1));
    int pos = atomicAdd(&cursor[d], 1);
    csr[pos] = make_int2(s, __float_as_int(n));
}

// ---------------- compute kernel ----------------

// one wave per node; lane = feature dim. Edge loop unrolled x8 with 4
// independent accumulators -> 8 gathers in flight per wave (MLP).
// WRITE_X0: hop-1 variant also writes the feature row to out column 0.
template <bool WRITE_X0>
__global__ __launch_bounds__(256) void k_hop(
    const float* __restrict__ prev, int pstride,
    float* __restrict__ next,        // row stride OUT_STRIDE
    float* __restrict__ x0out,       // only used when WRITE_X0
    const int* __restrict__ off, const int2* __restrict__ csr,
    const int* __restrict__ deg) {
    int wid = (blockIdx.x * blockDim.x + threadIdx.x) >> 6;
    int lane = threadIdx.x & 63;
    if (wid >= N_NODES) return;
    int e0 = off[wid], e1 = off[wid + 1];
    float self = prev[(size_t)wid * pstride + lane];
    if (WRITE_X0) x0out[(size_t)wid * OUT_STRIDE + lane] = self;
    float inv = 1.0f / (float)(deg[wid] + 1);  // self-loop coefficient
    float acc0 = inv * self;
    float acc1 = 0.f, acc2 = 0.f, acc3 = 0.f;
    int e = e0;
    for (; e + 8 <= e1; e += 8) {
        int2 c0 = csr[e + 0], c1 = csr[e + 1], c2 = csr[e + 2], c3 = csr[e + 3];
        int2 c4 = csr[e + 4], c5 = csr[e + 5], c6 = csr[e + 6], c7 = csr[e + 7];
        float p0 = prev[(size_t)c0.x * pstride + lane];
        float p1 = prev[(size_t)c1.x * pstride + lane];
        float p2 = prev[(size_t)c2.x * pstride + lane];
        float p3 = prev[(size_t)c3.x * pstride + lane];
        float p4 = prev[(size_t)c4.x * pstride + lane];
        float p5 = prev[(size_t)c5.x * pstride + lane];
        float p6 = prev[(size_t)c6.x * pstride + lane];
        float p7 = prev[(size_t)c7.x * pstride + lane];
        acc0 = fmaf(__int_as_float(c0.y), p0, acc0);
        acc1 = fmaf(__int_as_float(c1.y), p1, acc1);
        acc2 = fmaf(__int_as_float(c2.y), p2, acc2);
        acc3 = fmaf(__int_as_float(c3.y), p3, acc3);
        acc0 = fmaf(__int_as_float(c4.y), p4, acc0);
        acc1 = fmaf(__int_as_float(c5.y), p5, acc1);
        acc2 = fmaf(__int_as_float(c6.y), p6, acc2);
        acc3 = fmaf(__int_as_float(c7.y), p7, acc3);
    }
    if (e + 4 <= e1) {
        int2 c0 = csr[e + 0], c1 = csr[e + 1], c2 = csr[e + 2], c3 = csr[e + 3];
        float p0 = prev[(size_t)c0.x * pstride + lane];
        float p1 = prev[(size_t)c1.x * pstride + lane];
        float p2 = prev[(size_t)c2.x * pstride + lane];
        float p3 = prev[(size_t)c3.x * pstride + lane];
        acc0 = fmaf(__int_as_float(c0.y), p0, acc0);
        acc1 = fmaf(__int_as_float(c1.y), p1, acc1);
        acc2 = fmaf(__int_as_float(c2.y), p2, acc2);
        acc3 = fmaf(__int_as_float(c3.y), p3, acc3);
        e += 4;
    }
    for (; e < e1; ++e) {
        int2 c = csr[e];
        acc0 = fmaf(__int_as_float(c.y), prev[(size_t)c.x * pstride + lane], acc0);
    }
    next[(size_t)wid * OUT_STRIDE + lane] = (acc0 + acc1) + (acc2 + acc3);
}

// ---------------- launch ----------------

extern "C" void kernel_launch(void* const* d_in, const int* in_sizes, int n_in,
                              void* d_out, int out_size, void* d_ws, size_t ws_size,
                              hipStream_t stream) {
    const float* feature = (const float*)d_in[0];
    const int* edge = (const int*)d_in[1];
    const int* src = edge;            // edge_index[0]
    const int* dst = edge + N_EDGES;  // edge_index[1]
    float* out = (float*)d_out;
    char* ws = (char*)d_ws;

    int*  deg    = (int*)(ws + OFF_DEG);
    int*  hist   = (int*)(ws + OFF_HIST);
    int*  off    = (int*)(ws + OFF_OFFARR);
    int*  cursor = (int*)(ws + OFF_CURSOR);
    int*  bsum   = (int*)(ws + OFF_BSUM);
    int2* csr    = (int2*)(ws + OFF_CSR);

    const int TB = 256;
    // ---- build normalization + CSR (re-run every call: ws is re-poisoned)
    hipMemsetAsync(ws + OFF_DEG, 0, (size_t)2 * N_NODES * 4, stream);  // deg+hist
    k_count<<<(N_EDGES + TB - 1) / TB, TB, 0, stream>>>(src, dst, deg, hist);
    k_scan_sums<<<SCAN_NB, 256, 0, stream>>>(hist, bsum);
    k_scan_top<<<1, 64, 0, stream>>>(bsum);
    k_scan_down<<<SCAN_NB, 256, 0, stream>>>(hist, bsum, off, cursor);
    k_scatter<<<(N_EDGES + TB - 1) / TB, TB, 0, stream>>>(src, dst, deg, cursor, csr);
    // ---- K hops: hop k reads column block k-1 (hop 1 reads compact feature
    // and also writes x0 = feature into out column 0)
    const int hop_blocks = (N_NODES * 64 + TB - 1) / TB;  // 4 waves/block
    k_hop<true><<<hop_blocks, TB, 0, stream>>>(feature, D_FEAT, out + D_FEAT, out,
                                               off, csr, deg);
    for (int k = 2; k <= K_HOPS; ++k) {
        const float* prev = out + (size_t)(k - 1) * D_FEAT;
        float* next = out + (size_t)k * D_FEAT;
        k_hop<false><<<hop_blocks, TB, 0, stream>>>(prev, OUT_STRIDE, next, nullptr,
                                                    off, csr, deg);
    }
}

// Round 4
// 451.877 us; speedup vs baseline: 1.8766x; 1.0643x over previous
//
#include <hip/hip_runtime.h>
#include <hip/hip_fp16.h>

#define N_NODES 50000
#define N_EDGES 800000
#define D_FEAT 64
#define K_HOPS 8
#define OUT_STRIDE ((K_HOPS + 1) * D_FEAT)  // 576
#define NXCD 8

// ---------------- ws layout (bytes) ----------------
// degs+hists contiguous (one memset). XA overlays degs/hists/aux (dead after
// scatter; XA first written by hop 1, which runs after scatter).
#define ALIGN256(x) (((x) + 255) & ~(size_t)255)
static const size_t OFF_DEGS  = 0;                                          // int[8][N]
static const size_t OFF_HISTS = OFF_DEGS + (size_t)NXCD * N_NODES * 4;      // int[8][N]
static const size_t OFF_AUX   = ALIGN256(OFF_HISTS + (size_t)NXCD * N_NODES * 4); // int[E]
static const size_t OFF_XA    = 0;                                          // half[N*64] (overlay)
static const size_t OFF_DINV  = ALIGN256(OFF_AUX   + (size_t)N_EDGES * 4);  // float[N]
static const size_t OFF_OFF   = ALIGN256(OFF_DINV  + N_NODES * 4);          // int[N+1]
static const size_t OFF_BSUM  = ALIGN256(OFF_OFF   + (N_NODES + 1) * 4);    // int[64]
static const size_t OFF_BASES = ALIGN256(OFF_BSUM  + 64 * 4);               // int[8][N]
static const size_t OFF_CSR   = ALIGN256(OFF_BASES + (size_t)NXCD * N_NODES * 4); // int2[E]
static const size_t OFF_XB    = ALIGN256(OFF_CSR   + (size_t)N_EDGES * 8);  // half[N*64]

#define SCAN_BLOCK_ELEMS 1024
#define SCAN_NB ((N_NODES + SCAN_BLOCK_ELEMS - 1) / SCAN_BLOCK_ELEMS)  // 49

// HW_REG_XCC_ID = 20 (gfx940+); simm16 = (size-1)<<11 | offset<<6 | id
__device__ __forceinline__ unsigned xcc_id() {
    return __builtin_amdgcn_s_getreg((31u << 11) | 20u) & (NXCD - 1);
}

// ---------------- preprocessing kernels ----------------

// Per-XCD private histograms with workgroup-scope atomics: global atomics
// execute at L2; all atomics to copy x come from XCD x's L2 -> atomic, and
// no memory-side RMW round-trip. aux[e] records (xcd, slot-within-subbucket)
// so the scatter needs NO atomics.
__global__ void k_count(const int* __restrict__ src, const int* __restrict__ dst,
                        int* __restrict__ degs, int* __restrict__ hists,
                        int* __restrict__ aux) {
    int e = blockIdx.x * blockDim.x + threadIdx.x;
    if (e >= N_EDGES) return;
    int s = src[e], d = dst[e];
    if (s == d) { aux[e] = -1; return; }
    unsigned x = xcc_id();
    __hip_atomic_fetch_add(&degs[x * N_NODES + s], 1,
                           __ATOMIC_RELAXED, __HIP_MEMORY_SCOPE_WORKGROUP);
    int pw = __hip_atomic_fetch_add(&hists[x * N_NODES + d], 1,
                                    __ATOMIC_RELAXED, __HIP_MEMORY_SCOPE_WORKGROUP);
    aux[e] = (int)((x << 28) | (unsigned)pw);
}

__global__ void k_deg(const int* __restrict__ degs, float* __restrict__ dinv) {
    int i = blockIdx.x * blockDim.x + threadIdx.x;
    if (i >= N_NODES) return;
    int s = 1;  // self loop
    #pragma unroll
    for (int c = 0; c < NXCD; ++c) s += degs[c * N_NODES + i];
    dinv[i] = rsqrtf((float)s);
}

// scan stage 1: per-block sums of 1024-elem chunks (summed over 8 copies)
__global__ void k_scan_sums(const int* __restrict__ hists, int* __restrict__ bsum) {
    __shared__ int lds[256];
    int b = blockIdx.x, t = threadIdx.x;
    int base = b * SCAN_BLOCK_ELEMS;
    int s = 0;
    for (int j = t; j < SCAN_BLOCK_ELEMS; j += 256) {
        int idx = base + j;
        if (idx < N_NODES) {
            #pragma unroll
            for (int c = 0; c < NXCD; ++c) s += hists[c * N_NODES + idx];
        }
    }
    lds[t] = s; __syncthreads();
    for (int str = 128; str > 0; str >>= 1) {
        if (t < str) lds[t] += lds[t + str];
        __syncthreads();
    }
    if (t == 0) bsum[b] = lds[0];
}

// scan stage 2: single-wave exclusive scan of the 49 block sums
__global__ void k_scan_top(int* __restrict__ bsum) {
    int lane = threadIdx.x;  // blockDim = 64
    int orig = (lane < SCAN_NB) ? bsum[lane] : 0;
    int v = orig;
    for (int d = 1; d < 64; d <<= 1) {
        int u = __shfl_up(v, d, 64);
        if (lane >= d) v += u;
    }
    if (lane < SCAN_NB) bsum[lane] = v - orig;  // exclusive
}

// scan stage 3: down-sweep; writes off[] and per-(xcd,node) base offsets
__global__ void k_scan_down(const int* __restrict__ hists, const int* __restrict__ bsum,
                            int* __restrict__ off, int* __restrict__ bases) {
    __shared__ int lds[256];
    int b = blockIdx.x, t = threadIdx.x;
    int base = b * SCAN_BLOCK_ELEMS + t * 4;
    int tot[4];
    #pragma unroll
    for (int j = 0; j < 4; ++j) {
        int idx = base + j; int s = 0;
        if (idx < N_NODES) {
            #pragma unroll
            for (int c = 0; c < NXCD; ++c) s += hists[c * N_NODES + idx];
        }
        tot[j] = s;
    }
    int tsum = tot[0] + tot[1] + tot[2] + tot[3];
    lds[t] = tsum; __syncthreads();
    int x = tsum;
    for (int d = 1; d < 256; d <<= 1) {   // Hillis-Steele inclusive scan
        int u = (t >= d) ? lds[t - d] : 0;
        __syncthreads();
        x += u;
        lds[t] = x;
        __syncthreads();
    }
    int p = (x - tsum) + bsum[b];
    #pragma unroll
    for (int j = 0; j < 4; ++j) {
        int idx = base + j;
        if (idx < N_NODES) {
            off[idx] = p;
            #pragma unroll
            for (int c = 0; c < NXCD; ++c) {
                bases[c * N_NODES + idx] = p;
                p += hists[c * N_NODES + idx];
            }
        } else if (idx == N_NODES) {
            off[idx] = p;
        }
    }
}

// atomic-free scatter: slot = bases[xcd][d] + pos_within (from aux)
__global__ void k_scatter(const int* __restrict__ src, const int* __restrict__ dst,
                          const int* __restrict__ aux, const int* __restrict__ bases,
                          const float* __restrict__ dinv, int2* __restrict__ csr) {
    int e = blockIdx.x * blockDim.x + threadIdx.x;
    if (e >= N_EDGES) return;
    int a = aux[e];
    if (a < 0) return;  // self loop
    int s = src[e], d = dst[e];
    unsigned x = (unsigned)a >> 28;
    int pw = a & 0x0FFFFFFF;
    int pos = bases[x * N_NODES + d] + pw;
    csr[pos] = make_int2(s, __float_as_int(dinv[s] * dinv[d]));
}

// ---------------- compute kernels ----------------

// x0: feature -> out col 0 (fp32) and XB (fp16 compact, gather source for hop 1)
__global__ void k_x0half(const float4* __restrict__ feat4, float4* __restrict__ out4,
                         __half2* __restrict__ xh2) {
    int t = blockIdx.x * blockDim.x + threadIdx.x;  // over N*16
    if (t >= N_NODES * 16) return;
    int row = t >> 4, c = t & 15;
    float4 v = feat4[t];
    out4[(size_t)row * (OUT_STRIDE / 4) + c] = v;
    xh2[t * 2 + 0] = __floats2half2_rn(v.x, v.y);
    xh2[t * 2 + 1] = __floats2half2_rn(v.z, v.w);
}

// one wave per node; lane = feature dim. fp16 gather (one 128B line per row),
// 8-deep unroll with 4 independent accumulators for MLP. Output col fp32;
// also writes next fp16 gather buffer (except last hop).
template <bool WRITE_HALF>
__global__ __launch_bounds__(256) void k_hop(
    const __half* __restrict__ xin,
    float* __restrict__ outcol,      // out + k*64, row stride OUT_STRIDE
    __half* __restrict__ xout,
    const int* __restrict__ off, const int2* __restrict__ csr,
    const float* __restrict__ dinv) {
    int wid = (blockIdx.x * blockDim.x + threadIdx.x) >> 6;
    int lane = threadIdx.x & 63;
    if (wid >= N_NODES) return;
    int e0 = off[wid], e1 = off[wid + 1];
    float self = __half2float(xin[(size_t)wid * D_FEAT + lane]);
    float di = dinv[wid];
    float acc0 = di * di * self;  // self loop: 1/deg
    float acc1 = 0.f, acc2 = 0.f, acc3 = 0.f;
    int e = e0;
    for (; e + 8 <= e1; e += 8) {
        int2 c0 = csr[e + 0], c1 = csr[e + 1], c2 = csr[e + 2], c3 = csr[e + 3];
        int2 c4 = csr[e + 4], c5 = csr[e + 5], c6 = csr[e + 6], c7 = csr[e + 7];
        float p0 = __half2float(xin[(size_t)c0.x * D_FEAT + lane]);
        float p1 = __half2float(xin[(size_t)c1.x * D_FEAT + lane]);
        float p2 = __half2float(xin[(size_t)c2.x * D_FEAT + lane]);
        float p3 = __half2float(xin[(size_t)c3.x * D_FEAT + lane]);
        float p4 = __half2float(xin[(size_t)c4.x * D_FEAT + lane]);
        float p5 = __half2float(xin[(size_t)c5.x * D_FEAT + lane]);
        float p6 = __half2float(xin[(size_t)c6.x * D_FEAT + lane]);
        float p7 = __half2float(xin[(size_t)c7.x * D_FEAT + lane]);
        acc0 = fmaf(__int_as_float(c0.y), p0, acc0);
        acc1 = fmaf(__int_as_float(c1.y), p1, acc1);
        acc2 = fmaf(__int_as_float(c2.y), p2, acc2);
        acc3 = fmaf(__int_as_float(c3.y), p3, acc3);
        acc0 = fmaf(__int_as_float(c4.y), p4, acc0);
        acc1 = fmaf(__int_as_float(c5.y), p5, acc1);
        acc2 = fmaf(__int_as_float(c6.y), p6, acc2);
        acc3 = fmaf(__int_as_float(c7.y), p7, acc3);
    }
    if (e + 4 <= e1) {
        int2 c0 = csr[e + 0], c1 = csr[e + 1], c2 = csr[e + 2], c3 = csr[e + 3];
        float p0 = __half2float(xin[(size_t)c0.x * D_FEAT + lane]);
        float p1 = __half2float(xin[(size_t)c1.x * D_FEAT + lane]);
        float p2 = __half2float(xin[(size_t)c2.x * D_FEAT + lane]);
        float p3 = __half2float(xin[(size_t)c3.x * D_FEAT + lane]);
        acc0 = fmaf(__int_as_float(c0.y), p0, acc0);
        acc1 = fmaf(__int_as_float(c1.y), p1, acc1);
        acc2 = fmaf(__int_as_float(c2.y), p2, acc2);
        acc3 = fmaf(__int_as_float(c3.y), p3, acc3);
        e += 4;
    }
    for (; e < e1; ++e) {
        int2 c = csr[e];
        acc0 = fmaf(__int_as_float(c.y),
                    __half2float(xin[(size_t)c.x * D_FEAT + lane]), acc0);
    }
    float r = (acc0 + acc1) + (acc2 + acc3);
    outcol[(size_t)wid * OUT_STRIDE + lane] = r;
    if (WRITE_HALF) xout[(size_t)wid * D_FEAT + lane] = __float2half_rn(r);
}

// ---------------- launch ----------------

extern "C" void kernel_launch(void* const* d_in, const int* in_sizes, int n_in,
                              void* d_out, int out_size, void* d_ws, size_t ws_size,
                              hipStream_t stream) {
    const float* feature = (const float*)d_in[0];
    const int* edge = (const int*)d_in[1];
    const int* src = edge;            // edge_index[0]
    const int* dst = edge + N_EDGES;  // edge_index[1]
    float* out = (float*)d_out;
    char* ws = (char*)d_ws;

    int*    degs  = (int*)(ws + OFF_DEGS);
    int*    hists = (int*)(ws + OFF_HISTS);
    int*    aux   = (int*)(ws + OFF_AUX);
    float*  dinv  = (float*)(ws + OFF_DINV);
    int*    off   = (int*)(ws + OFF_OFF);
    int*    bsum  = (int*)(ws + OFF_BSUM);
    int*    bases = (int*)(ws + OFF_BASES);
    int2*   csr   = (int2*)(ws + OFF_CSR);
    __half* xa    = (__half*)(ws + OFF_XA);  // overlays degs/hists/aux (dead by then)
    __half* xb    = (__half*)(ws + OFF_XB);

    const int TB = 256;
    // ---- build normalization + CSR (re-run every call: ws is re-poisoned)
    hipMemsetAsync(ws + OFF_DEGS, 0, (size_t)2 * NXCD * N_NODES * 4, stream);
    k_x0half<<<(N_NODES * 16 + TB - 1) / TB, TB, 0, stream>>>(
        (const float4*)feature, (float4*)out, (__half2*)xb);
    k_count<<<(N_EDGES + TB - 1) / TB, TB, 0, stream>>>(src, dst, degs, hists, aux);
    k_deg<<<(N_NODES + TB - 1) / TB, TB, 0, stream>>>(degs, dinv);
    k_scan_sums<<<SCAN_NB, 256, 0, stream>>>(hists, bsum);
    k_scan_top<<<1, 64, 0, stream>>>(bsum);
    k_scan_down<<<SCAN_NB, 256, 0, stream>>>(hists, bsum, off, bases);
    k_scatter<<<(N_EDGES + TB - 1) / TB, TB, 0, stream>>>(src, dst, aux, bases,
                                                          dinv, csr);
    // ---- K hops, fp16 ping-pong gather buffers (XB -> XA -> XB -> ...)
    const int hop_blocks = (N_NODES * 64 + TB - 1) / TB;  // 4 waves/block
    for (int k = 1; k <= K_HOPS; ++k) {
        const __half* xin = (k & 1) ? xb : xa;
        __half* xout      = (k & 1) ? xa : xb;
        float* outcol = out + (size_t)k * D_FEAT;
        if (k < K_HOPS)
            k_hop<true><<<hop_blocks, TB, 0, stream>>>(xin, outcol, xout, off, csr, dinv);
        else
            k_hop<false><<<hop_blocks, TB, 0, stream>>>(xin, outcol, nullptr, off, csr, dinv);
    }
}